// Round 4
// baseline (45271.594 us; speedup 1.0000x reference)
//
#include <hip/hip_runtime.h>

#define Hh 512
#define Bb 256
#define Tt 512
#define NPR 128
#define BH (Bb*Hh)            // 131072 elems
#define WN (4*Hh*Hh)          // 1048576 elems per weight matrix
#define BM 64
#define BK 64

typedef __attribute__((ext_vector_type(8))) short bf8;
typedef __attribute__((ext_vector_type(4))) float f4;

__device__ __forceinline__ unsigned short f2bf(float x) {
  unsigned u = __float_as_uint(x);
  return (unsigned short)((u + 0x7FFFu + ((u >> 16) & 1u)) >> 16);
}
__device__ __forceinline__ float bf2f(unsigned short h) {
  return __uint_as_float((unsigned)h << 16);
}

struct CellP {
  const unsigned short *A1h, *A1l, *W1h, *W1l;   // GEMM1
  const unsigned short *A2h, *A2l, *W2h, *W2l;   // optional GEMM2
  const float* bias;                              // (4H)
  const float* svec; long long sstr;              // scalar input s[b]=svec[b*sstr]
  const float* sW;                                // (4H) column for scalar input
  const unsigned short *pHh, *pHl;                // pred mode
  const float *linW, *linb;
  float* predOut; int predStride;
  const float* cin; float* cout;                  // fp32 c state
  unsigned short *hOh, *hOl;                      // bf16 hi/lo h output
  int active;
};

// wave wv stages tensor wv: 0=A-hi 1=A-lo 2=W-hi 3=W-lo. Chunk = 64 rows x 64 k.
__device__ __forceinline__ void stage_load(const CellP& p, int cc, int wv, int lane,
                                           int m0, int j0, uint4* stg) {
  const int gm = cc >> 3;
  const int k0 = (cc & 7) * BK;
  const unsigned short* s;
  if      (wv == 0) s = gm ? p.A2h : p.A1h;
  else if (wv == 1) s = gm ? p.A2l : p.A1l;
  else if (wv == 2) s = gm ? p.W2h : p.W1h;
  else              s = gm ? p.W2l : p.W1l;
  const bool isW = wv >= 2;
  #pragma unroll
  for (int i = 0; i < 8; ++i) {
    const int rl   = i*8 + (lane >> 3);
    const int rowg = isW ? ((rl >> 4)*Hh + j0 + (rl & 15)) : (m0 + rl);
    const size_t off = (size_t)rowg*Hh + k0 + (lane & 7)*8;
    stg[i] = *(const uint4*)(s + off);
  }
}

__device__ __forceinline__ void stage_write(char* lbase, int wv, int lane, const uint4* stg) {
  char* t = lbase + wv*8192;
  #pragma unroll
  for (int i = 0; i < 8; ++i) {
    const int rl = i*8 + (lane >> 3);
    const int sl = (lane & 7) ^ (rl & 7);          // XOR swizzle (T2)
    *(uint4*)(t + rl*128 + sl*16) = stg[i];
  }
}

__device__ __forceinline__ void chunk_compute(const char* B, int wv, int lane, f4* acc) {
  const int r15 = lane & 15, kg = lane >> 4, sx = r15 & 7;
  const int arow = (16*wv + r15) * 128;
  #pragma unroll
  for (int ks = 0; ks < 2; ++ks) {
    const int sl = (((ks*4) + kg) ^ sx) * 16;
    const bf8 a_h = *(const bf8*)(B +        arow + sl);
    const bf8 a_l = *(const bf8*)(B + 8192 + arow + sl);
    #pragma unroll
    for (int g = 0; g < 4; ++g) {
      const int wrow = (16*g + r15) * 128;
      const bf8 w_h = *(const bf8*)(B + 16384 + wrow + sl);
      const bf8 w_l = *(const bf8*)(B + 24576 + wrow + sl);
      acc[g] = __builtin_amdgcn_mfma_f32_16x16x32_bf16(a_h, w_h, acc[g], 0, 0, 0);
      acc[g] = __builtin_amdgcn_mfma_f32_16x16x32_bf16(a_l, w_h, acc[g], 0, 0, 0);
      acc[g] = __builtin_amdgcn_mfma_f32_16x16x32_bf16(a_h, w_l, acc[g], 0, 0, 0);
    }
  }
}

__global__ __launch_bounds__(256) void lstm_stage(CellP pa, CellP pb) {
  __shared__ uint4 lds4[4096];                 // 64KB: 2 x {Ahi 8K, Alo 8K, Whi 8K, Wlo 8K}
  const CellP p = (blockIdx.x >= 128) ? pb : pa;
  if (!p.active) return;

  const int blk = blockIdx.x & 127;
  const int m0  = (blk & 3) * BM;              // 4 m-blocks of 64 batch rows
  const int j0  = (blk >> 2) * 16;             // 32 j-blocks of 16 hidden cols
  const int tid = threadIdx.x;
  const int wv  = tid >> 6, lane = tid & 63;
  char* L = (char*)lds4;

  uint4 stg[8];
  stage_load(p, 0, wv, lane, m0, j0, stg);     // prologue loads in flight

  // ---- scalar-input phase: per-thread s for row (m0 + tid>>2) ----
  float sval = 0.f;
  const bool hasS = (p.svec != nullptr) || (p.pHh != nullptr);
  if (p.svec != nullptr) {
    sval = p.svec[(size_t)(m0 + (tid >> 2)) * p.sstr];
  } else if (p.pHh != nullptr) {
    const int bg = m0 + (tid >> 2), part = tid & 3;
    const unsigned short* ph = p.pHh + (size_t)bg*Hh + part*128;
    const unsigned short* pl = p.pHl + (size_t)bg*Hh + part*128;
    const float* lw = p.linW + part*128;
    float a = 0.f;
    #pragma unroll 4
    for (int q = 0; q < 128; q += 8) {
      const bf8 vh = *(const bf8*)(ph + q);
      const bf8 vl = *(const bf8*)(pl + q);
      #pragma unroll
      for (int e = 0; e < 8; ++e)
        a = fmaf(bf2f((unsigned short)vh[e]) + bf2f((unsigned short)vl[e]), lw[q+e], a);
    }
    a += __shfl_xor(a, 1, 64);
    a += __shfl_xor(a, 2, 64);
    sval = a + p.linb[0];
    if (p.predOut != nullptr && j0 == 0 && part == 0)
      p.predOut[(size_t)bg * p.predStride] = sval;
  }

  f4 acc[4];
  #pragma unroll
  for (int g = 0; g < 4; ++g) acc[g] = (f4){0.f,0.f,0.f,0.f};

  const int CC = (p.A2h != nullptr) ? 16 : 8;  // chunks (8 per gemm)
  for (int c = 0; c < CC; ++c) {
    stage_write(L + (c & 1)*32768, wv, lane, stg);   // waits vmcnt on stg
    __syncthreads();
    if (c + 1 < CC) stage_load(p, c+1, wv, lane, m0, j0, stg);  // async under compute
    chunk_compute(L + (c & 1)*32768, wv, lane, acc);
  }

  // ---- epilogue: gates -> c,h ----
  const int r15 = lane & 15, kg = lane >> 4;
  const int j = j0 + r15;
  float swv[4] = {0.f,0.f,0.f,0.f};
  if (p.sW != nullptr) {
    swv[0] = p.sW[j];        swv[1] = p.sW[Hh + j];
    swv[2] = p.sW[2*Hh + j]; swv[3] = p.sW[3*Hh + j];
  }
  const float bi  = p.bias[j],        bfv = p.bias[Hh + j];
  const float bgv = p.bias[2*Hh + j], bo  = p.bias[3*Hh + j];
  #pragma unroll
  for (int r = 0; r < 4; ++r) {
    const float sv = hasS ? __shfl(sval, ((kg*4 + r) << 2), 64) : 0.f;
    const int b = m0 + 16*wv + kg*4 + r;
    const size_t idx = (size_t)b*Hh + j;
    const float gi = acc[0][r] + bi  + sv*swv[0];
    const float gf = acc[1][r] + bfv + sv*swv[1];
    const float gg = acc[2][r] + bgv + sv*swv[2];
    const float go = acc[3][r] + bo  + sv*swv[3];
    const float si = 1.f/(1.f + expf(-gi));
    const float sf = 1.f/(1.f + expf(-gf));
    const float so = 1.f/(1.f + expf(-go));
    const float c2 = sf * p.cin[idx] + si * tanhf(gg);
    const float h2 = so * tanhf(c2);
    p.cout[idx] = c2;
    const unsigned short hh = f2bf(h2);
    p.hOh[idx] = hh;
    p.hOl[idx] = f2bf(h2 - bf2f(hh));
  }
}

__global__ __launch_bounds__(256) void conv_w(const float* __restrict__ src,
                                              unsigned short* __restrict__ hi,
                                              unsigned short* __restrict__ lo) {
  const int i = (blockIdx.x * 256 + threadIdx.x) * 4;   // WN = 1M, grid 1024
  const float4 v = *(const float4*)(src + i);
  const unsigned short h0 = f2bf(v.x), h1 = f2bf(v.y), h2 = f2bf(v.z), h3 = f2bf(v.w);
  ushort4 hv; hv.x = h0; hv.y = h1; hv.z = h2; hv.w = h3;
  ushort4 lv;
  lv.x = f2bf(v.x - bf2f(h0)); lv.y = f2bf(v.y - bf2f(h1));
  lv.z = f2bf(v.z - bf2f(h2)); lv.w = f2bf(v.w - bf2f(h3));
  *(ushort4*)(hi + i) = hv;
  *(ushort4*)(lo + i) = lv;
}

__global__ __launch_bounds__(64) void final_pred(const unsigned short* __restrict__ hh,
                                                 const unsigned short* __restrict__ hl,
                                                 const float* __restrict__ linW,
                                                 const float* __restrict__ linb,
                                                 float* __restrict__ out) {
  const int b = blockIdx.x;
  const int lane = threadIdx.x;
  const int k0 = lane * 8;
  const bf8 vh = *(const bf8*)(hh + (size_t)b * Hh + k0);
  const bf8 vl = *(const bf8*)(hl + (size_t)b * Hh + k0);
  float a = 0.f;
  #pragma unroll
  for (int e = 0; e < 8; ++e)
    a = fmaf(bf2f((unsigned short)vh[e]) + bf2f((unsigned short)vl[e]), linW[k0 + e], a);
  #pragma unroll
  for (int off = 1; off < 64; off <<= 1) a += __shfl_xor(a, off, 64);
  if (lane == 0) out[(size_t)b * NPR + (NPR - 1)] = a + linb[0];
}

extern "C" void kernel_launch(void* const* d_in, const int* in_sizes, int n_in,
                              void* d_out, int out_size, void* d_ws, size_t ws_size,
                              hipStream_t stream) {
  const float* x     = (const float*)d_in[0];
  const float* eWih0 = (const float*)d_in[1];
  const float* eWhh0 = (const float*)d_in[2];
  const float* eb0   = (const float*)d_in[3];
  const float* eWih1 = (const float*)d_in[4];
  const float* eWhh1 = (const float*)d_in[5];
  const float* eb1   = (const float*)d_in[6];
  const float* dWih0 = (const float*)d_in[7];
  const float* dWhh0 = (const float*)d_in[8];
  const float* db0   = (const float*)d_in[9];
  const float* dWih1 = (const float*)d_in[10];
  const float* dWhh1 = (const float*)d_in[11];
  const float* db1   = (const float*)d_in[12];
  const float* linW  = (const float*)d_in[13];
  const float* linb  = (const float*)d_in[14];
  float* out = (float*)d_out;

  // ---- workspace layout ----
  unsigned short* wb = (unsigned short*)d_ws;
  unsigned short* eWhh0h = wb + 0*(size_t)WN;  unsigned short* eWhh0l = wb + 1*(size_t)WN;
  unsigned short* eWih1h = wb + 2*(size_t)WN;  unsigned short* eWih1l = wb + 3*(size_t)WN;
  unsigned short* eWhh1h = wb + 4*(size_t)WN;  unsigned short* eWhh1l = wb + 5*(size_t)WN;
  unsigned short* dWhh0h = wb + 6*(size_t)WN;  unsigned short* dWhh0l = wb + 7*(size_t)WN;
  unsigned short* dWih1h = wb + 8*(size_t)WN;  unsigned short* dWih1l = wb + 9*(size_t)WN;
  unsigned short* dWhh1h = wb + 10*(size_t)WN; unsigned short* dWhh1l = wb + 11*(size_t)WN;
  unsigned short* sb = wb + 12*(size_t)WN;
  unsigned short* h0h[2] = { sb + 0*(size_t)BH, sb + 1*(size_t)BH };
  unsigned short* h0l[2] = { sb + 2*(size_t)BH, sb + 3*(size_t)BH };
  unsigned short* h1h[2] = { sb + 4*(size_t)BH, sb + 5*(size_t)BH };
  unsigned short* h1l[2] = { sb + 6*(size_t)BH, sb + 7*(size_t)BH };
  float* cbase = (float*)(sb + 8*(size_t)BH);
  float* c0 = cbase;
  float* c1 = cbase + BH;

  (void)hipMemsetAsync(h0h[0], 0, (size_t)BH*2, stream);
  (void)hipMemsetAsync(h0l[0], 0, (size_t)BH*2, stream);
  (void)hipMemsetAsync(h1h[0], 0, (size_t)BH*2, stream);
  (void)hipMemsetAsync(h1l[0], 0, (size_t)BH*2, stream);
  (void)hipMemsetAsync(c0, 0, (size_t)BH*4, stream);
  (void)hipMemsetAsync(c1, 0, (size_t)BH*4, stream);

  conv_w<<<1024, 256, 0, stream>>>(eWhh0, eWhh0h, eWhh0l);
  conv_w<<<1024, 256, 0, stream>>>(eWih1, eWih1h, eWih1l);
  conv_w<<<1024, 256, 0, stream>>>(eWhh1, eWhh1h, eWhh1l);
  conv_w<<<1024, 256, 0, stream>>>(dWhh0, dWhh0h, dWhh0l);
  conv_w<<<1024, 256, 0, stream>>>(dWih1, dWih1h, dWih1l);
  conv_w<<<1024, 256, 0, stream>>>(dWhh1, dWhh1h, dWhh1l);

  CellP off = {};   // all null / inactive

  // ---- encoder: stage s runs L0(t=s) || L1(t=s-1) ----
  for (int s = 0; s <= Tt; ++s) {
    CellP pa = off, pb = off;
    if (s < Tt) {
      pa.active = 1;
      pa.A1h = h0h[s&1]; pa.A1l = h0l[s&1]; pa.W1h = eWhh0h; pa.W1l = eWhh0l;
      pa.bias = eb0;
      pa.svec = x + s; pa.sstr = Tt; pa.sW = eWih0;
      pa.cin = c0; pa.cout = c0;
      pa.hOh = h0h[(s+1)&1]; pa.hOl = h0l[(s+1)&1];
    }
    if (s >= 1) {
      const int u = s - 1;
      pb.active = 1;
      pb.A1h = h1h[u&1]; pb.A1l = h1l[u&1]; pb.W1h = eWhh1h; pb.W1l = eWhh1l;
      pb.A2h = h0h[s&1]; pb.A2l = h0l[s&1]; pb.W2h = eWih1h; pb.W2l = eWih1l;
      pb.bias = eb1;
      pb.cin = c1; pb.cout = c1;
      pb.hOh = h1h[(u+1)&1]; pb.hOl = h1l[(u+1)&1];
    }
    lstm_stage<<<256, 256, 0, stream>>>(pa, pb);
  }

  // ---- decoder: 128 steps x 2 dependent cells ----
  for (int i = 0; i < NPR; ++i) {
    CellP p0 = off;
    p0.active = 1;
    p0.A1h = h0h[i&1]; p0.A1l = h0l[i&1]; p0.W1h = dWhh0h; p0.W1l = dWhh0l;
    p0.bias = db0; p0.sW = dWih0;
    if (i == 0) { p0.svec = x + (Tt - 1); p0.sstr = Tt; }
    else {
      p0.pHh = h1h[i&1]; p0.pHl = h1l[i&1]; p0.linW = linW; p0.linb = linb;
      p0.predOut = out + (i-1); p0.predStride = NPR;
    }
    p0.cin = c0; p0.cout = c0;
    p0.hOh = h0h[(i+1)&1]; p0.hOl = h0l[(i+1)&1];
    lstm_stage<<<128, 256, 0, stream>>>(p0, off);

    CellP p1 = off;
    p1.active = 1;
    p1.A1h = h1h[i&1]; p1.A1l = h1l[i&1]; p1.W1h = dWhh1h; p1.W1l = dWhh1l;
    p1.A2h = h0h[(i+1)&1]; p1.A2l = h0l[(i+1)&1]; p1.W2h = dWih1h; p1.W2l = dWih1l;
    p1.bias = db1;
    p1.cin = c1; p1.cout = c1;
    p1.hOh = h1h[(i+1)&1]; p1.hOl = h1l[(i+1)&1];
    lstm_stage<<<128, 256, 0, stream>>>(p1, off);
  }

  final_pred<<<Bb, 64, 0, stream>>>(h1h[NPR&1], h1l[NPR&1], linW, linb, out);
  (void)in_sizes; (void)n_in; (void)out_size; (void)ws_size;
}